// Round 3
// baseline (279.857 us; speedup 1.0000x reference)
//
#include <hip/hip_runtime.h>
#include <math.h>

#define DKD 256
#define DVD 256

constexpr int TPB   = 256;          // 4 waves/block
constexpr int NB    = 1024;         // blocks; NB * RPB == M
constexpr int RPB   = 128;          // rows per block
constexpr int WPB   = 4;            // waves per block
constexpr int RPW   = 32;           // rows per wave
constexpr int ITERS = 8;            // 4 rows per iter (one per 16-lane group)
constexpr float SHIFT = 64.0f;      // fixed softmax shift; logit max ~72 (9.5-sigma to overflow)

__device__ __forceinline__ float dot4(const float4 a, const float4 b) {
    return a.x*b.x + a.y*b.y + a.z*b.z + a.w*b.w;
}
__device__ __forceinline__ float xgrp(float x) {    // sum across the 4 16-lane groups
    x += __shfl_xor(x, 16);
    x += __shfl_xor(x, 32);
    return x;
}

// One pass over K and V. Per iteration each 16-lane group handles one row:
// lane (g,p) loads K/V columns (j*16+p)*4..+3 (j=0..3) -> 256B contiguous per group
// per load inst. Dot-reduce via intra-row DPP shuffles. No LDS / barriers in loop.
__global__ __launch_bounds__(TPB, 4) void k_fused(
    const float* __restrict__ q,
    const float* __restrict__ K,
    const float* __restrict__ V,
    float* __restrict__ partT,   // [DVD][NB]
    float* __restrict__ psum)    // [NB]
{
    __shared__ __align__(16) float4 s_acc[WPB][64];
    __shared__ float s_S[WPB];

    const int t    = threadIdx.x;
    const int lane = t & 63;
    const int wave = t >> 6;
    const int g    = lane >> 4;        // row-within-iteration
    const int p    = lane & 15;        // position within row
    const int b    = blockIdx.x;

    const float4* __restrict__ K4 = (const float4*)K;
    const float4* __restrict__ V4 = (const float4*)V;

    // q fragment (same for every row): columns (j*16+p)*4 .. +3
    float4 q4[4];
    #pragma unroll
    for (int j = 0; j < 4; ++j) q4[j] = ((const float4*)q)[j * 16 + p];

    const int    rbase = b * RPB + wave * RPW + g;   // this lane's first row
    const size_t lb    = (size_t)rbase * 64 + p;     // float4 index

    float4 acc[4];
    #pragma unroll
    for (int j = 0; j < 4; ++j) acc[j] = make_float4(0.f, 0.f, 0.f, 0.f);
    float Ssum = 0.f;

    // register double-buffer; fully unrolled -> static indices (no scratch)
    float4 kbuf[2][4], vbuf[2][4];
    #pragma unroll
    for (int j = 0; j < 4; ++j) {
        kbuf[0][j] = K4[lb + j * 16];
        vbuf[0][j] = V4[lb + j * 16];
    }

    #pragma unroll
    for (int it = 0; it < ITERS; ++it) {
        const int cur = it & 1, nxt = cur ^ 1;
        if (it + 1 < ITERS) {                          // prefetch next 4 rows
            const size_t nb_ = lb + (size_t)(it + 1) * 256;   // 4 rows = 256 float4
            #pragma unroll
            for (int j = 0; j < 4; ++j) {
                kbuf[nxt][j] = K4[nb_ + j * 16];
                vbuf[nxt][j] = V4[nb_ + j * 16];
            }
        }

        float s = dot4(kbuf[cur][0], q4[0]) + dot4(kbuf[cur][1], q4[1])
                + dot4(kbuf[cur][2], q4[2]) + dot4(kbuf[cur][3], q4[3]);
        s += __shfl_xor(s, 1);
        s += __shfl_xor(s, 2);
        s += __shfl_xor(s, 4);
        s += __shfl_xor(s, 8);                         // row logit in all 16 lanes

        const float e = __expf(s - SHIFT);
        Ssum += e;

        #pragma unroll
        for (int j = 0; j < 4; ++j) {
            acc[j].x += e * vbuf[cur][j].x;
            acc[j].y += e * vbuf[cur][j].y;
            acc[j].z += e * vbuf[cur][j].z;
            acc[j].w += e * vbuf[cur][j].w;
        }
    }

    // epilogue: sum the 4 groups' disjoint row-sets (same columns)
    #pragma unroll
    for (int j = 0; j < 4; ++j) {
        acc[j].x = xgrp(acc[j].x);
        acc[j].y = xgrp(acc[j].y);
        acc[j].z = xgrp(acc[j].z);
        acc[j].w = xgrp(acc[j].w);
    }
    Ssum = xgrp(Ssum);

    if (lane < 16) {
        #pragma unroll
        for (int j = 0; j < 4; ++j) s_acc[wave][j * 16 + lane] = acc[j];
    }
    if (lane == 0) s_S[wave] = Ssum;
    __syncthreads();

    // cross-wave reduce: thread t owns output column t
    const float* saf = (const float*)&s_acc[0][0];
    const float yv = saf[t] + saf[256 + t] + saf[512 + t] + saf[768 + t];
    partT[(size_t)t * NB + b] = yv;
    if (t == 0) psum[b] = s_S[0] + s_S[1] + s_S[2] + s_S[3];
}

// out[j] = (sum_b partT[j][b]) / (sum_b psum[b])   (all partials share the SHIFT frame)
__global__ __launch_bounds__(TPB) void k_combine(
    const float* __restrict__ partT,
    const float* __restrict__ psum,
    float* __restrict__ out)
{
    __shared__ float red[TPB];
    const int t = threadIdx.x;

    const float4 ps = ((const float4*)psum)[t];       // NB/4 == TPB
    red[t] = ps.x + ps.y + ps.z + ps.w;
    __syncthreads();
    for (int s = TPB / 2; s > 0; s >>= 1) {
        if (t < s) red[t] += red[t + s];
        __syncthreads();
    }
    const float invL = 1.0f / red[0];
    __syncthreads();

    const int j = blockIdx.x;
    const float4 v = ((const float4*)(partT + (size_t)j * NB))[t];
    red[t] = v.x + v.y + v.z + v.w;
    __syncthreads();
    for (int s = TPB / 2; s > 0; s >>= 1) {
        if (t < s) red[t] += red[t + s];
        __syncthreads();
    }
    if (t == 0) out[j] = red[0] * invL;
}

extern "C" void kernel_launch(void* const* d_in, const int* in_sizes, int n_in,
                              void* d_out, int out_size, void* d_ws, size_t ws_size,
                              hipStream_t stream) {
    const float* q = (const float*)d_in[0];
    const float* K = (const float*)d_in[1];
    const float* V = (const float*)d_in[2];
    float* out = (float*)d_out;

    // ws: partT[DVD*NB] | psum[NB]
    float* ws    = (float*)d_ws;
    float* partT = ws;
    float* psum  = partT + (size_t)DVD * NB;

    k_fused  <<<NB,  TPB, 0, stream>>>(q, K, V, partT, psum);
    k_combine<<<DVD, TPB, 0, stream>>>(partT, psum, out);
}

// Round 4
// 261.878 us; speedup vs baseline: 1.0687x; 1.0687x over previous
//
#include <hip/hip_runtime.h>
#include <math.h>

#define DKD 256
#define DVD 256

constexpr int TPB   = 256;          // 4 waves/block
constexpr int NB    = 2048;         // blocks; NB * RPB == M ; 2 residency generations
constexpr int RPB   = 64;           // rows per block
constexpr int WPB   = 4;            // waves per block
constexpr int RPW   = 16;           // rows per wave
constexpr int ITERS = RPW / 4;      // 4 rows per iter (one per 16-lane group)
constexpr int TPBC  = 512;          // combine block size (NB/4 == 512)
constexpr float SHIFT = 64.0f;      // fixed softmax shift; logit max ~72 (9.5-sigma to overflow)

typedef float floatx4 __attribute__((ext_vector_type(4)));

__device__ __forceinline__ float4 ntload4(const float4* p) {
    floatx4 v = __builtin_nontemporal_load((const floatx4*)p);
    return make_float4(v.x, v.y, v.z, v.w);
}
__device__ __forceinline__ float dot4(const float4 a, const float4 b) {
    return a.x*b.x + a.y*b.y + a.z*b.z + a.w*b.w;
}
__device__ __forceinline__ float xgrp(float x) {    // sum across the 4 16-lane groups
    x += __shfl_xor(x, 16);
    x += __shfl_xor(x, 32);
    return x;
}

// Single pass over K and V, register-only inner loop, NT loads (L3 bypass).
// Per iteration each 16-lane group handles one row; lane (g,p) covers columns
// (j*16+p)*4..+3, j=0..3 (256B contiguous per group per load inst).
__global__ __launch_bounds__(TPB, 4) void k_fused(
    const float* __restrict__ q,
    const float* __restrict__ K,
    const float* __restrict__ V,
    float* __restrict__ partT,   // [DVD][NB]
    float* __restrict__ psum)    // [NB]
{
    __shared__ __align__(16) float4 s_acc[WPB][64];
    __shared__ float s_S[WPB];

    const int t    = threadIdx.x;
    const int lane = t & 63;
    const int wave = t >> 6;
    const int g    = lane >> 4;
    const int p    = lane & 15;
    const int b    = blockIdx.x;

    const float4* __restrict__ K4 = (const float4*)K;
    const float4* __restrict__ V4 = (const float4*)V;

    float4 q4[4];
    #pragma unroll
    for (int j = 0; j < 4; ++j) q4[j] = ((const float4*)q)[j * 16 + p];

    const int    rbase = b * RPB + wave * RPW + g;
    const size_t lb    = (size_t)rbase * 64 + p;

    float4 acc[4];
    #pragma unroll
    for (int j = 0; j < 4; ++j) acc[j] = make_float4(0.f, 0.f, 0.f, 0.f);
    float Ssum = 0.f;

    // 2-stage register pipeline, fully unrolled (static indices only)
    float4 kbuf[2][4], vbuf[2][4];
    #pragma unroll
    for (int j = 0; j < 4; ++j) {
        kbuf[0][j] = ntload4(&K4[lb + j * 16]);
        vbuf[0][j] = ntload4(&V4[lb + j * 16]);
    }

    #pragma unroll
    for (int it = 0; it < ITERS; ++it) {
        const int cur = it & 1, nxt = cur ^ 1;
        if (it + 1 < ITERS) {                              // prefetch next 4 rows
            const size_t nb_ = lb + (size_t)(it + 1) * 256;
            #pragma unroll
            for (int j = 0; j < 4; ++j) {
                kbuf[nxt][j] = ntload4(&K4[nb_ + j * 16]);
                vbuf[nxt][j] = ntload4(&V4[nb_ + j * 16]);
            }
        }

        float s = dot4(kbuf[cur][0], q4[0]) + dot4(kbuf[cur][1], q4[1])
                + dot4(kbuf[cur][2], q4[2]) + dot4(kbuf[cur][3], q4[3]);
        s += __shfl_xor(s, 1);
        s += __shfl_xor(s, 2);
        s += __shfl_xor(s, 4);
        s += __shfl_xor(s, 8);                             // row logit in all 16 lanes

        const float e = __expf(s - SHIFT);
        Ssum += e;

        #pragma unroll
        for (int j = 0; j < 4; ++j) {
            acc[j].x += e * vbuf[cur][j].x;
            acc[j].y += e * vbuf[cur][j].y;
            acc[j].z += e * vbuf[cur][j].z;
            acc[j].w += e * vbuf[cur][j].w;
        }
    }

    // epilogue: sum the 4 groups (disjoint rows, same columns)
    #pragma unroll
    for (int j = 0; j < 4; ++j) {
        acc[j].x = xgrp(acc[j].x);
        acc[j].y = xgrp(acc[j].y);
        acc[j].z = xgrp(acc[j].z);
        acc[j].w = xgrp(acc[j].w);
    }
    Ssum = xgrp(Ssum);

    if (lane < 16) {
        #pragma unroll
        for (int j = 0; j < 4; ++j) s_acc[wave][j * 16 + lane] = acc[j];
    }
    if (lane == 0) s_S[wave] = Ssum;
    __syncthreads();

    const float* saf = (const float*)&s_acc[0][0];
    const float yv = saf[t] + saf[256 + t] + saf[512 + t] + saf[768 + t];
    partT[(size_t)t * NB + b] = yv;
    if (t == 0) psum[b] = s_S[0] + s_S[1] + s_S[2] + s_S[3];
}

// out[j] = (sum_b partT[j][b]) / (sum_b psum[b])   (all partials share the SHIFT frame)
__global__ __launch_bounds__(TPBC) void k_combine(
    const float* __restrict__ partT,
    const float* __restrict__ psum,
    float* __restrict__ out)
{
    __shared__ float red[TPBC];
    const int t = threadIdx.x;

    const float4 ps = ((const float4*)psum)[t];       // NB/4 == TPBC
    red[t] = ps.x + ps.y + ps.z + ps.w;
    __syncthreads();
    for (int s = TPBC / 2; s > 0; s >>= 1) {
        if (t < s) red[t] += red[t + s];
        __syncthreads();
    }
    const float invL = 1.0f / red[0];
    __syncthreads();

    const int j = blockIdx.x;
    const float4 v = ((const float4*)(partT + (size_t)j * NB))[t];
    red[t] = v.x + v.y + v.z + v.w;
    __syncthreads();
    for (int s = TPBC / 2; s > 0; s >>= 1) {
        if (t < s) red[t] += red[t + s];
        __syncthreads();
    }
    if (t == 0) out[j] = red[0] * invL;
}

extern "C" void kernel_launch(void* const* d_in, const int* in_sizes, int n_in,
                              void* d_out, int out_size, void* d_ws, size_t ws_size,
                              hipStream_t stream) {
    const float* q = (const float*)d_in[0];
    const float* K = (const float*)d_in[1];
    const float* V = (const float*)d_in[2];
    float* out = (float*)d_out;

    // ws: partT[DVD*NB] | psum[NB]
    float* ws    = (float*)d_ws;
    float* partT = ws;
    float* psum  = partT + (size_t)DVD * NB;

    k_fused  <<<NB,  TPB,  0, stream>>>(q, K, V, partT, psum);
    k_combine<<<DVD, TPBC, 0, stream>>>(partT, psum, out);
}

// Round 6
// 246.559 us; speedup vs baseline: 1.1351x; 1.0621x over previous
//
#include <hip/hip_runtime.h>
#include <math.h>

#define DKD 256
#define DVD 256

constexpr int TPB  = 256;    // 4 waves/block
constexpr int NB1  = 2048;   // k_logits blocks; NB1 * RPB == M
constexpr int RPB  = 64;     // rows per k_logits block
constexpr int NB2  = 256;    // phase2 blocks
constexpr int RP2  = 512;    // rows per phase2 block (M / NB2)
constexpr float THRESH = 35.0f;   // drop rows with l < M_g - 35: <1e-10 relative mass

typedef float floatx4 __attribute__((ext_vector_type(4)));

__device__ __forceinline__ float4 ntload4(const float4* p) {
    floatx4 v = __builtin_nontemporal_load((const floatx4*)p);
    return make_float4(v.x, v.y, v.z, v.w);
}
__device__ __forceinline__ float dot4(const float4 a, const float4 b) {
    return a.x*b.x + a.y*b.y + a.z*b.z + a.w*b.w;
}

// ---- Kernel 1: logits = K . q  (pure NT K-stream, register pipeline) ----
// 16-lane group per row; lane (g,p) covers columns (j*16+p)*4..+3, j=0..3.
__global__ __launch_bounds__(TPB, 4) void k_logits(
    const float* __restrict__ q,
    const float* __restrict__ K,
    float* __restrict__ logits,
    float* __restrict__ pmax)    // [NB1] per-block max
{
    __shared__ float s_wred[4];

    const int t    = threadIdx.x;
    const int lane = t & 63;
    const int wave = t >> 6;
    const int g    = lane >> 4;
    const int p    = lane & 15;
    const int b    = blockIdx.x;

    const float4* __restrict__ K4 = (const float4*)K;

    float4 q4[4];
    #pragma unroll
    for (int j = 0; j < 4; ++j) q4[j] = ((const float4*)q)[j * 16 + p];

    const int    rbase = b * RPB + wave * 16 + g;
    const size_t lb    = (size_t)rbase * 64 + p;

    float4 kbuf[2][4];
    #pragma unroll
    for (int j = 0; j < 4; ++j) kbuf[0][j] = ntload4(&K4[lb + j * 16]);

    float wmax = -INFINITY;
    #pragma unroll
    for (int it = 0; it < 4; ++it) {                 // 4 iters x 4 rows/wave
        const int cur = it & 1, nxt = cur ^ 1;
        if (it + 1 < 4) {
            const size_t nb_ = lb + (size_t)(it + 1) * 256;   // 4 rows = 256 float4
            #pragma unroll
            for (int j = 0; j < 4; ++j) kbuf[nxt][j] = ntload4(&K4[nb_ + j * 16]);
        }
        float s = dot4(kbuf[cur][0], q4[0]) + dot4(kbuf[cur][1], q4[1])
                + dot4(kbuf[cur][2], q4[2]) + dot4(kbuf[cur][3], q4[3]);
        s += __shfl_xor(s, 1);
        s += __shfl_xor(s, 2);
        s += __shfl_xor(s, 4);
        s += __shfl_xor(s, 8);                       // row logit in all 16 lanes

        if (p == 0) logits[rbase + it * 4] = s;      // rbase already includes g
        wmax = fmaxf(wmax, s);
    }

    // block max: across groups, then across waves
    wmax = fmaxf(wmax, __shfl_xor(wmax, 16));
    wmax = fmaxf(wmax, __shfl_xor(wmax, 32));
    if (lane == 0) s_wred[wave] = wmax;
    __syncthreads();
    if (t == 0)
        pmax[b] = fmaxf(fmaxf(s_wred[0], s_wred[1]), fmaxf(s_wred[2], s_wred[3]));
}

// ---- Kernel 2: global max, exact denominator, sparse weighted-V gather ----
__global__ __launch_bounds__(TPB) void k_phase2(
    const float* __restrict__ logits,
    const float* __restrict__ pmax,
    const float* __restrict__ V,
    float* __restrict__ part,    // [NB2][DVD]
    float* __restrict__ pS)      // [NB2]
{
    __shared__ float red[TPB];
    __shared__ int   s_idx[RP2];
    __shared__ float s_e[RP2];
    __shared__ int   s_cnt;

    const int t = threadIdx.x;
    const int b = blockIdx.x;

    // global max (redundant per block; pmax is 8 KB, L2-hot)
    float m = -INFINITY;
    for (int i = t; i < NB1; i += TPB) m = fmaxf(m, pmax[i]);
    red[t] = m; __syncthreads();
    for (int s = TPB / 2; s > 0; s >>= 1) {
        if (t < s) red[t] = fmaxf(red[t], red[t + s]);
        __syncthreads();
    }
    const float Mg = red[0];
    if (t == 0) s_cnt = 0;
    __syncthreads();

    // scan this block's logit chunk: exact sum over all rows, gather big rows
    float ssum = 0.f;
    const int base = b * RP2;
    #pragma unroll
    for (int i = t; i < RP2; i += TPB) {             // 2 iters
        const float l = logits[base + i];
        const float e = __expf(l - Mg);
        ssum += e;
        if (l > Mg - THRESH) {
            const int k = atomicAdd(&s_cnt, 1);      // LDS atomic
            s_idx[k] = base + i;
            s_e[k]   = e;
        }
    }
    __syncthreads();
    const int cnt = s_cnt;

    // cooperative weighted V accumulation: thread t owns output column t
    float acc = 0.f;
    for (int i = 0; i < cnt; ++i)
        acc += s_e[i] * V[(size_t)s_idx[i] * DVD + t];   // 1KB coalesced row read
    part[(size_t)b * DVD + t] = acc;

    red[t] = ssum; __syncthreads();
    for (int s = TPB / 2; s > 0; s >>= 1) {
        if (t < s) red[t] += red[t + s];
        __syncthreads();
    }
    if (t == 0) pS[b] = red[0];
}

// ---- Kernel 3: out[j] = (sum_b part[b][j]) / (sum_b pS[b]) ----
__global__ __launch_bounds__(TPB) void k_combine(
    const float* __restrict__ part,
    const float* __restrict__ pS,
    float* __restrict__ out)
{
    __shared__ float red[TPB];
    const int t = threadIdx.x;

    red[t] = pS[t];                                   // NB2 == TPB
    __syncthreads();
    for (int s = TPB / 2; s > 0; s >>= 1) {
        if (t < s) red[t] += red[t + s];
        __syncthreads();
    }
    const float invL = 1.0f / red[0];

    float y0 = 0.f, y1 = 0.f, y2 = 0.f, y3 = 0.f;
    #pragma unroll 4
    for (int c = 0; c < NB2; c += 4) {
        y0 += part[(size_t)(c + 0) * DVD + t];
        y1 += part[(size_t)(c + 1) * DVD + t];
        y2 += part[(size_t)(c + 2) * DVD + t];
        y3 += part[(size_t)(c + 3) * DVD + t];
    }
    out[t] = (y0 + y1 + y2 + y3) * invL;
}

extern "C" void kernel_launch(void* const* d_in, const int* in_sizes, int n_in,
                              void* d_out, int out_size, void* d_ws, size_t ws_size,
                              hipStream_t stream) {
    const float* q = (const float*)d_in[0];
    const float* K = (const float*)d_in[1];
    const float* V = (const float*)d_in[2];
    float* out = (float*)d_out;

    // in_sizes are ELEMENT counts (round-0 proven): M = elems(K) / DK
    const int M = in_sizes[1] / DKD;   // 131072
    (void)M;

    // ws layout: small fixed arrays FIRST so a bad M can never overlap them.
    // pmax[NB1] | part[NB2*DVD] | pS[NB2] | logits[M]
    float* ws     = (float*)d_ws;
    float* pmax   = ws;
    float* part   = pmax + NB1;
    float* pS     = part + (size_t)NB2 * DVD;
    float* logits = pS + NB2;

    k_logits <<<NB1, TPB, 0, stream>>>(q, K, logits, pmax);
    k_phase2 <<<NB2, TPB, 0, stream>>>(logits, pmax, V, part, pS);
    k_combine<<<1,   TPB, 0, stream>>>(part, pS, out);
}